// Round 6
// baseline (12.213 us; speedup 1.0000x reference)
//
#include <hip/hip_runtime.h>

// ContrastiveLoss collapses to:
//   v = sum_i mask_i * latent_i / max(||latent_i||, eps)   (64-vector)
//   out = COF1 * (||v||^2 - sum(mask)) / (2N)
// O(N*d), ~2 MB traffic -> launch/latency bound. Two dispatches (round-4
// lesson: in-kernel grid handshake costs more than a 2nd graph node).
// This round: one memory round-trip per kernel.

#define EPSV 1e-8f
#define COF1 0.01f

constexpr int N_ROWS = 8192;
constexpr int DIM = 64;
constexpr int TPB = 256;
constexpr int WPB = TPB / 64;                     // 4 waves/block
constexpr int BLOCKS = 64;                        // 256 waves, 64 partial slots
constexpr int RPW = N_ROWS / (BLOCKS * WPB);      // 32 rows/wave -> 8 float4 batches
constexpr int SLOT = 68;                          // v[64] + cnt + pad (16B align)

// Kernel 1: lane L -> row-group g=L>>4, column quad c4=L&15. All 8 batches'
// float4 loads issued up-front (one memory round trip, 32 VGPRs staging);
// 8 independent shuffle chains overlap. Block combines 4 waves in LDS ->
// one 68-float slot.
__global__ __launch_bounds__(TPB, 2) void cl_partial(const float* __restrict__ latent,
                                                     float* __restrict__ ws) {
    const int wv   = threadIdx.x >> 6;
    const int lane = threadIdx.x & 63;
    const int g    = lane >> 4;
    const int c4   = lane & 15;
    const int row0 = (blockIdx.x * WPB + wv) * RPW;

    const float4* lat4 = (const float4*)latent;

    float4 x[RPW / 4];
    #pragma unroll
    for (int b = 0; b < RPW / 4; ++b)
        x[b] = lat4[(row0 + b * 4 + g) * (DIM / 4) + c4];

    float4 v = make_float4(0.f, 0.f, 0.f, 0.f);
    float cnt = 0.0f;
    #pragma unroll
    for (int b = 0; b < RPW / 4; ++b) {
        float s = x[b].x + x[b].y + x[b].z + x[b].w;
        float q = x[b].x * x[b].x + x[b].y * x[b].y + x[b].z * x[b].z + x[b].w * x[b].w;
        #pragma unroll
        for (int off = 8; off; off >>= 1) {       // reduce within 16-lane row group
            s += __shfl_xor(s, off);
            q += __shfl_xor(q, off);
        }
        if (s != 0.0f) {
            float inv = 1.0f / fmaxf(sqrtf(q), EPSV);
            v.x += x[b].x * inv; v.y += x[b].y * inv;
            v.z += x[b].z * inv; v.w += x[b].w * inv;
            if (c4 == 0) cnt += 1.0f;             // one count per row
        }
    }
    #pragma unroll
    for (int off = 16; off <= 32; off <<= 1) {    // combine the 4 row-groups
        v.x += __shfl_xor(v.x, off); v.y += __shfl_xor(v.y, off);
        v.z += __shfl_xor(v.z, off); v.w += __shfl_xor(v.w, off);
        cnt += __shfl_xor(cnt, off);
    }

    __shared__ float4 sv4[WPB][16];
    __shared__ float  scnt[WPB];
    if (lane < 16) sv4[wv][c4] = v;
    if (lane == 0) scnt[wv] = cnt;
    __syncthreads();

    if (wv == 0 && lane < 16) {
        float4 a = sv4[0][c4];
        float4 b1 = sv4[1][c4], b2 = sv4[2][c4], b3 = sv4[3][c4];
        a.x += b1.x + b2.x + b3.x; a.y += b1.y + b2.y + b3.y;
        a.z += b1.z + b2.z + b3.z; a.w += b1.w + b2.w + b3.w;
        ((float4*)(ws + blockIdx.x * SLOT))[c4] = a;
        if (lane == 0)
            ws[blockIdx.x * SLOT + 64] = scnt[0] + scnt[1] + scnt[2] + scnt[3];
    }
}

// Kernel 2: ONE wave. 16 float4 loads cover all 64 slots x 64 components
// (lane: g=slot-group, c4=column quad; slot s=4j+g), + 64 scalar count
// loads — all in flight in one round trip. Cross-lane combine, finalize.
__global__ __launch_bounds__(64) void cl_final(const float* __restrict__ ws,
                                               float* __restrict__ out) {
    const int lane = threadIdx.x;                  // 64 threads = 1 wave
    const int g    = lane >> 4;
    const int c4   = lane & 15;
    const float4* ws4 = (const float4*)ws;         // 17 float4 per slot

    float4 f[16];
    #pragma unroll
    for (int j = 0; j < 16; ++j)                   // slot s = 4*j + g
        f[j] = ws4[(4 * j + g) * (SLOT / 4) + c4];
    float c = ws[lane * SLOT + 64];                // slot 'lane' count

    float4 vq = make_float4(0.f, 0.f, 0.f, 0.f);
    #pragma unroll
    for (int j = 0; j < 16; ++j) {
        vq.x += f[j].x; vq.y += f[j].y; vq.z += f[j].z; vq.w += f[j].w;
    }
    // combine slot-groups g=0..3 (lanes with equal c4)
    #pragma unroll
    for (int off = 16; off <= 32; off <<= 1) {
        vq.x += __shfl_xor(vq.x, off); vq.y += __shfl_xor(vq.y, off);
        vq.z += __shfl_xor(vq.z, off); vq.w += __shfl_xor(vq.w, off);
    }
    // total count over all 64 slots
    #pragma unroll
    for (int off = 32; off; off >>= 1)
        c += __shfl_xor(c, off);

    // ||v||^2: per-lane quad dot, then sum over the 16 distinct c4 in-group
    float d = vq.x * vq.x + vq.y * vq.y + vq.z * vq.z + vq.w * vq.w;
    #pragma unroll
    for (int off = 8; off; off >>= 1)
        d += __shfl_xor(d, off);

    if (lane == 0)
        out[0] = COF1 * (d - c) / (2.0f * (float)N_ROWS);
}

extern "C" void kernel_launch(void* const* d_in, const int* in_sizes, int n_in,
                              void* d_out, int out_size, void* d_ws, size_t ws_size,
                              hipStream_t stream) {
    const float* latent = (const float*)d_in[0];
    float* out = (float*)d_out;
    float* ws = (float*)d_ws;   // 64*68*4 = 17,408 bytes

    cl_partial<<<BLOCKS, TPB, 0, stream>>>(latent, ws);
    cl_final<<<1, 64, 0, stream>>>(ws, out);
}